// Round 15
// baseline (105.161 us; speedup 1.0000x reference)
//
#include <hip/hip_runtime.h>
#include <hip/hip_bf16.h>

typedef __bf16 bf16x8 __attribute__((ext_vector_type(8)));
typedef __bf16 bf16x4 __attribute__((ext_vector_type(4)));
typedef float  f32x4  __attribute__((ext_vector_type(4)));

#define HF 128          // hidden dim
#define W1K 256         // W1 inner dim (2H)

// ====== Kernel 1 (v16): v15 + W loaded directly from W1 (no repack pass) ===
// u[n] = A . x_src[n],  v[n] = B . x_dst[n]   (b1 added in k2)
// R14 conclusion: k1 pinned at ~3.2 TB/s mixed-traffic ceiling across 7
// structural designs (occupancy/depth/LDS/reg variants). Remaining cost is
// dispatch overhead: fold the one-time W-fragment load into the prologue
// (64 strided f32x4 loads per wave, L3-hot) and drop the repack kernel.
__global__ __launch_bounds__(512, 1) void node_precompute16(
    const float* __restrict__ x_src, const float* __restrict__ x_dst,
    const float* __restrict__ W1,
    __bf16* __restrict__ u, __bf16* __restrict__ v, int nNodes)
{
    __shared__ __align__(16) float xlds[8][4][1024];   // 8 waves x 4 x 4 KiB

    const int tid  = threadIdx.x;
    const int lane = tid & 63;
    const int wid  = tid >> 6;      // 0..7
    const int l15  = lane & 15;
    const int lg   = lane >> 4;

    const int h = wid & 1;          // waves alternate halves
    const float* __restrict__ xh = h ? x_dst : x_src;
    __bf16* __restrict__ oph = h ? v : u;

    // ---- one-time: this half's 32 W fragments into 128 VGPRs (from W1) ----
    // frag f = mt*4+kk : W[h*128 + ...][row = mt*16+l15][k = kk*32+lg*8 ..+8]
    bf16x8 wfrag[32];
    {
        const float* Wh = W1 + h * HF;
        #pragma unroll
        for (int f = 0; f < 32; ++f) {
            const int mt = f >> 2;
            const int kk = f & 3;
            const float* p = Wh + (size_t)(mt * 16 + l15) * W1K + kk * 32 + lg * 8;
            f32x4 a = *reinterpret_cast<const f32x4*>(p);
            f32x4 b = *reinterpret_cast<const f32x4*>(p + 4);
            bf16x8 w8;
            #pragma unroll
            for (int i = 0; i < 4; ++i) {
                w8[i]     = (__bf16)a[i];
                w8[i + 4] = (__bf16)b[i];
            }
            wfrag[f] = w8;
        }
    }

    const int nst    = nNodes >> 3;        // 12500 8-node subtiles (exact)
    const int stride = gridDim.x * 4;      // wave-slots per half

    // ---- async stage: subtile st -> xlds[wid][buf]; 4 x 16B per lane ----
    // granule G = i*64+lane in [0,256): row = G>>5 (0..7), q = G&31.
    // linear LDS dest; source pre-swizzled q^row (rule 21).
    auto STAGE = [&](int buf, int st) {
        float* dst0 = &xlds[wid][buf][0];
        #pragma unroll
        for (int i = 0; i < 4; ++i) {
            const int G   = i * 64 + lane;
            const int row = G >> 5;
            const int q   = G & 31;
            const int qs  = q ^ row;
            const int grow = min(st * 8 + row, nNodes - 1);
            const float* src = xh + (size_t)grow * HF + qs * 4;
            __builtin_amdgcn_global_load_lds(
                (const __attribute__((address_space(1))) void*)src,
                (__attribute__((address_space(3))) void*)(dst0 + (size_t)G * 4),
                16, 0, 0);
        }
    };

    int st = blockIdx.x * 4 + (wid >> 1);
    if (st >= nst) return;

    STAGE(0, st);
    if (st + stride     < nst) STAGE(1, st + stride);
    if (st + 2 * stride < nst) STAGE(2, st + 2 * stride);

    int it = 0;
    int bcur = 0;
    const int row_l = l15 & 7;     // lanes 8..15 alias rows 0..7 (broadcast)
    while (st < nst) {
        const int st1 = st + stride;
        const int st2 = st + 2 * stride;
        const int st3 = st + 3 * stride;
        const bool h1 = (st1 < nst), h2 = (st2 < nst), h3 = (st3 < nst);
        if (h3) STAGE((bcur + 3) & 3, st3);

        // exact wait for L(cur); stores never waited in steady state
        const int P = (int)h1 + (int)h2 + (int)h3;
        if (P == 3) {
            if (it >= 3)      asm volatile("s_waitcnt vmcnt(36)" ::: "memory");
            else if (it == 2) asm volatile("s_waitcnt vmcnt(28)" ::: "memory");
            else if (it == 1) asm volatile("s_waitcnt vmcnt(20)" ::: "memory");
            else              asm volatile("s_waitcnt vmcnt(12)" ::: "memory");
        } else if (P == 2) {
            asm volatile("s_waitcnt vmcnt(8)" ::: "memory");
        } else if (P == 1) {
            asm volatile("s_waitcnt vmcnt(4)" ::: "memory");
        } else {
            asm volatile("s_waitcnt vmcnt(0)" ::: "memory");
        }
        __builtin_amdgcn_sched_barrier(0);

        f32x4 acc[8];
        #pragma unroll
        for (int mt = 0; mt < 8; ++mt) acc[mt] = (f32x4){0.f, 0.f, 0.f, 0.f};

        const float* xr = &xlds[wid][bcur][(size_t)row_l * 128];
        #pragma unroll
        for (int kk = 0; kk < 4; ++kk) {
            const int q0 = kk * 8 + lg * 2;
            f32x4 a0 = *reinterpret_cast<const f32x4*>(xr + ((q0)     ^ row_l) * 4);
            f32x4 a1 = *reinterpret_cast<const f32x4*>(xr + ((q0 + 1) ^ row_l) * 4);
            bf16x8 xb;
            #pragma unroll
            for (int i = 0; i < 4; ++i) {
                xb[i]     = (__bf16)a0[i];
                xb[i + 4] = (__bf16)a1[i];
            }
            #pragma unroll
            for (int mt = 0; mt < 8; ++mt)
                acc[mt] = __builtin_amdgcn_mfma_f32_16x16x32_bf16(
                    wfrag[mt * 4 + kk], xb, acc[mt], 0, 0, 0);
        }

        // store: node = st*8 + l15 (l15<8), channels mt*16 + lg*4 .. +4
        if (l15 < 8) {
            const int node = st * 8 + l15;
            __bf16* op = oph + (size_t)node * HF + lg * 4;
            #pragma unroll
            for (int mt = 0; mt < 8; ++mt) {
                bf16x4 o4;
                #pragma unroll
                for (int r = 0; r < 4; ++r) o4[r] = (__bf16)acc[mt][r];
                *reinterpret_cast<bf16x4*>(op + mt * 16) = o4;
            }
        }

        bcur = (bcur + 1) & 3;
        st = st1;
        ++it;
    }
}

// ================= Kernel 2: per-edge score (pure gather, 4 edges/sub) =====
// score[e] = W2 . relu(u[src[e]] + v[dst[e]] + b1) + b2
__global__ __launch_bounds__(256) void edge_score_kernel(
    const __bf16* __restrict__ u, const __bf16* __restrict__ v,
    const int* __restrict__ sidx, const int* __restrict__ didx,
    const float* __restrict__ W2, const float* __restrict__ b1,
    const float* __restrict__ b2,
    float* __restrict__ out, int nEdges)
{
    const int tid = threadIdx.x;
    const int sub = tid >> 4;        // 0..15
    const int l16 = tid & 15;

    const int ebase = blockIdx.x * 64 + sub;   // edges ebase + {0,16,32,48}

    float w2v[8], b1v[8];
    #pragma unroll
    for (int j = 0; j < 8; ++j) {
        w2v[j] = W2[l16 * 8 + j];
        b1v[j] = b1[l16 * 8 + j];
    }
    const float b2v = b2[0];

    int e[4], si[4], di[4];
    #pragma unroll
    for (int q = 0; q < 4; ++q) {
        e[q] = ebase + q * 16;
        const int c = min(e[q], nEdges - 1);
        si[q] = sidx[c];
        di[q] = didx[c];
    }

    bf16x8 uv[4], vv[4];
    #pragma unroll
    for (int q = 0; q < 4; ++q) {
        uv[q] = *reinterpret_cast<const bf16x8*>(u + (size_t)si[q] * HF + l16 * 8);
        vv[q] = *reinterpret_cast<const bf16x8*>(v + (size_t)di[q] * HF + l16 * 8);
    }

    float s[4] = {0.f, 0.f, 0.f, 0.f};
    #pragma unroll
    for (int q = 0; q < 4; ++q)
        #pragma unroll
        for (int j = 0; j < 8; ++j)
            s[q] += fmaxf((float)uv[q][j] + (float)vv[q][j] + b1v[j], 0.f) * w2v[j];

    #pragma unroll
    for (int off = 1; off < 16; off <<= 1)
        #pragma unroll
        for (int q = 0; q < 4; ++q)
            s[q] += __shfl_xor(s[q], off, 64);

    if (l16 == 0) {
        #pragma unroll
        for (int q = 0; q < 4; ++q)
            if (e[q] < nEdges) out[e[q]] = s[q] + b2v;
    }
}

// ================= Fallback: fused single kernel (round-1) =================
__global__ __launch_bounds__(256, 2) void edge_mlp_kernel(
    const float* __restrict__ x_src, const float* __restrict__ x_dst,
    const int*   __restrict__ src_idx, const int* __restrict__ dst_idx,
    const float* __restrict__ W1, const float* __restrict__ b1,
    const float* __restrict__ W2, const float* __restrict__ b2,
    float* __restrict__ out, int nEdges)
{
    __shared__ __align__(16) __bf16 w1lds[64 * 64 * 8];

    const int tid  = threadIdx.x;
    const int lane = tid & 63;
    const int wid  = tid >> 6;
    const int l15  = lane & 15;
    const int lg   = lane >> 4;

    for (int p = wid; p < 64; p += 4) {
        const int n   = p >> 3;
        const int kk  = p & 7;
        const float* src = W1 + (n * 16 + l15) * W1K + kk * 32 + lg * 8;
        bf16x8 w8;
        #pragma unroll
        for (int i = 0; i < 8; ++i) w8[i] = (__bf16)src[i];
        *reinterpret_cast<bf16x8*>(&w1lds[(p * 64 + lane) * 8]) = w8;
    }
    __syncthreads();

    float w2v[8], b1v[8];
    #pragma unroll
    for (int n = 0; n < 8; ++n) {
        w2v[n] = W2[n * 16 + l15];
        b1v[n] = b1[n * 16 + l15];
    }
    const float b2v = b2[0];

    const int ntiles = nEdges / 256;
    for (int t = blockIdx.x; t < ntiles; t += gridDim.x) {
        const int ebase = t * 256 + wid * 64;

        const float* srow[4];
        const float* drow[4];
        #pragma unroll
        for (int m = 0; m < 4; ++m) {
            const int e  = ebase + m * 16 + l15;
            srow[m] = x_src + (size_t)src_idx[e] * HF + lg * 8;
            drow[m] = x_dst + (size_t)dst_idx[e] * HF + lg * 8;
        }

        f32x4 acc[4][8];
        #pragma unroll
        for (int m = 0; m < 4; ++m)
            #pragma unroll
            for (int n = 0; n < 8; ++n)
                acc[m][n] = (f32x4){0.f, 0.f, 0.f, 0.f};

        #pragma unroll
        for (int kk = 0; kk < 8; ++kk) {
            bf16x8 a[4];
            #pragma unroll
            for (int m = 0; m < 4; ++m) {
                const float* p = (kk < 4) ? (srow[m] + kk * 32)
                                          : (drow[m] + (kk - 4) * 32);
                f32x4 u0 = *reinterpret_cast<const f32x4*>(p);
                f32x4 u1 = *reinterpret_cast<const f32x4*>(p + 4);
                bf16x8 av;
                #pragma unroll
                for (int i = 0; i < 4; ++i) {
                    av[i]     = (__bf16)u0[i];
                    av[i + 4] = (__bf16)u1[i];
                }
                a[m] = av;
            }
            #pragma unroll
            for (int n = 0; n < 8; ++n) {
                bf16x8 bfrag = *reinterpret_cast<const bf16x8*>(
                    &w1lds[((n * 8 + kk) * 64 + lane) * 8]);
                #pragma unroll
                for (int m = 0; m < 4; ++m) {
                    acc[m][n] = __builtin_amdgcn_mfma_f32_16x16x32_bf16(
                        a[m], bfrag, acc[m][n], 0, 0, 0);
                }
            }
        }

        #pragma unroll
        for (int m = 0; m < 4; ++m) {
            float part[4];
            #pragma unroll
            for (int r = 0; r < 4; ++r) {
                float s = 0.f;
                #pragma unroll
                for (int n = 0; n < 8; ++n) {
                    float hv = acc[m][n][r] + b1v[n];
                    s += fmaxf(hv, 0.f) * w2v[n];
                }
                part[r] = s;
            }
            #pragma unroll
            for (int off = 1; off < 16; off <<= 1) {
                #pragma unroll
                for (int r = 0; r < 4; ++r)
                    part[r] += __shfl_xor(part[r], off, 64);
            }
            if (l15 == m) {
                f32x4 v4 = { part[0] + b2v, part[1] + b2v,
                             part[2] + b2v, part[3] + b2v };
                *reinterpret_cast<f32x4*>(&out[ebase + m * 16 + lg * 4]) = v4;
            }
        }
    }
}

extern "C" void kernel_launch(void* const* d_in, const int* in_sizes, int n_in,
                              void* d_out, int out_size, void* d_ws, size_t ws_size,
                              hipStream_t stream) {
    const float* x_src  = (const float*)d_in[0];
    const float* x_dst  = (const float*)d_in[1];
    const int*   sidx   = (const int*)d_in[2];
    const int*   didx   = (const int*)d_in[3];
    const float* W1     = (const float*)d_in[4];
    const float* b1     = (const float*)d_in[5];
    const float* W2     = (const float*)d_in[6];
    const float* b2     = (const float*)d_in[7];
    float* out = (float*)d_out;

    const int nEdges = in_sizes[2];
    const int nNodes = in_sizes[0] / HF;

    const size_t uvsz   = (size_t)2 * nNodes * HF;                  // elems
    const size_t needed = uvsz * sizeof(__bf16);                    // u+v
    if (ws_size >= needed && (nNodes & 7) == 0) {
        __bf16* u  = (__bf16*)d_ws;
        __bf16* v  = u + (size_t)nNodes * HF;

        node_precompute16<<<256, 512, 0, stream>>>(
            x_src, x_dst, W1, u, v, nNodes);

        const int egrid = (nEdges + 63) / 64;
        edge_score_kernel<<<egrid, 256, 0, stream>>>(
            u, v, sidx, didx, W2, b1, b2, out, nEdges);
    } else {
        edge_mlp_kernel<<<512, 256, 0, stream>>>(
            x_src, x_dst, sidx, didx, W1, b1, W2, b2, out, nEdges);
    }
}

// Round 16
// 81.586 us; speedup vs baseline: 1.2890x; 1.2890x over previous
//
#include <hip/hip_runtime.h>
#include <hip/hip_bf16.h>

typedef __bf16 bf16x8 __attribute__((ext_vector_type(8)));
typedef __bf16 bf16x4 __attribute__((ext_vector_type(4)));
typedef float  f32x4  __attribute__((ext_vector_type(4)));

#define HF 128          // hidden dim
#define W1K 256         // W1 inner dim (2H)

// ========== Kernel 0: one-time repack W1 fp32 -> bf16 MFMA-A-fragment order
// wf layout: [h][f=mt*4+kk][lane][8 bf16]; frag = W[h][mt*16+l15][kk*32+lg*8..+8]
// KEEP THIS KERNEL: R15 showed folding these strided reads into k1's prologue
// (per-wave) costs +55us; the separate contiguous repack costs ~2us.
__global__ __launch_bounds__(256) void w1_repack(
    const float* __restrict__ W1, __bf16* __restrict__ wf)
{
    const int h    = blockIdx.x;        // 0 -> A (u), 1 -> B (v)
    const int tid  = threadIdx.x;
    const int lane = tid & 63;
    const int wid  = tid >> 6;
    const int l15  = lane & 15;
    const int lg   = lane >> 4;

    for (int f = wid; f < 32; f += 4) {
        const int mt = f >> 2;
        const int kk = f & 3;
        const float* p = W1 + h * HF + (size_t)(mt * 16 + l15) * W1K
                       + kk * 32 + lg * 8;
        f32x4 a = *reinterpret_cast<const f32x4*>(p);
        f32x4 b = *reinterpret_cast<const f32x4*>(p + 4);
        bf16x8 w8;
        #pragma unroll
        for (int i = 0; i < 4; ++i) {
            w8[i]     = (__bf16)a[i];
            w8[i + 4] = (__bf16)b[i];
        }
        *reinterpret_cast<bf16x8*>(wf + ((size_t)(h * 32 + f) * 64 + lane) * 8) = w8;
    }
}

// ====== Kernel 1 (v14, best measured): reg-W + depth-2 async pipeline ======
// u[n] = A . x_src[n],  v[n] = B . x_dst[n]   (b1 added in k2)
// Best total (R13: 80.5us). 8 waves/block, W in 128 VGPRs from pre-packed
// wf, 8-node private tiles triple-buffered, barrier-free, counted vmcnt.
__global__ __launch_bounds__(512, 1) void node_precompute14(
    const float* __restrict__ x_src, const float* __restrict__ x_dst,
    const __bf16* __restrict__ wf,
    __bf16* __restrict__ u, __bf16* __restrict__ v, int nNodes)
{
    __shared__ __align__(16) float xlds[8][3][1024];   // 8 waves x 3 x 4 KiB

    const int tid  = threadIdx.x;
    const int lane = tid & 63;
    const int wid  = tid >> 6;      // 0..7
    const int l15  = lane & 15;
    const int lg   = lane >> 4;

    const int h = wid & 1;          // waves alternate halves
    const float* __restrict__ xh = h ? x_dst : x_src;
    __bf16* __restrict__ oph = h ? v : u;

    // ---- one-time: this half's 32 W fragments into 128 VGPRs (L3-hot) ----
    bf16x8 wfrag[32];
    {
        const __bf16* wsrc = wf + ((size_t)h * 32 * 64 + lane) * 8;
        #pragma unroll
        for (int f = 0; f < 32; ++f)
            wfrag[f] = *reinterpret_cast<const bf16x8*>(wsrc + (size_t)f * 64 * 8);
    }

    const int nst    = nNodes >> 3;        // 12500 8-node subtiles (exact)
    const int stride = gridDim.x * 4;      // wave-slots per half

    // ---- async stage: subtile st -> xlds[wid][buf]; 4 x 16B per lane ----
    // granule G = i*64+lane in [0,256): row = G>>5 (0..7), q = G&31.
    // linear LDS dest; source pre-swizzled q^row (rule 21).
    auto STAGE = [&](int buf, int st) {
        float* dst0 = &xlds[wid][buf][0];
        #pragma unroll
        for (int i = 0; i < 4; ++i) {
            const int G   = i * 64 + lane;
            const int row = G >> 5;
            const int q   = G & 31;
            const int qs  = q ^ row;
            const int grow = min(st * 8 + row, nNodes - 1);
            const float* src = xh + (size_t)grow * HF + qs * 4;
            __builtin_amdgcn_global_load_lds(
                (const __attribute__((address_space(1))) void*)src,
                (__attribute__((address_space(3))) void*)(dst0 + (size_t)G * 4),
                16, 0, 0);
        }
    };

    int st = blockIdx.x * 4 + (wid >> 1);
    if (st >= nst) return;

    STAGE(0, st);
    if (st + stride < nst) STAGE(1, st + stride);

    int it = 0;
    int bcur = 0;
    const int row_l = l15 & 7;     // lanes 8..15 alias rows 0..7 (broadcast)
    while (st < nst) {
        const int st1 = st + stride;
        const int st2 = st + 2 * stride;
        const bool hn = (st1 < nst);
        const bool ha = (st2 < nst);
        if (ha) STAGE((bcur + 2) % 3, st2);

        if (it == 0) {
            if (ha)      asm volatile("s_waitcnt vmcnt(8)"  ::: "memory");
            else if (hn) asm volatile("s_waitcnt vmcnt(4)"  ::: "memory");
            else         asm volatile("s_waitcnt vmcnt(0)"  ::: "memory");
        } else {
            if (ha)      asm volatile("s_waitcnt vmcnt(16)" ::: "memory");
            else if (hn) asm volatile("s_waitcnt vmcnt(12)" ::: "memory");
            else         asm volatile("s_waitcnt vmcnt(8)"  ::: "memory");
        }
        __builtin_amdgcn_sched_barrier(0);

        f32x4 acc[8];
        #pragma unroll
        for (int mt = 0; mt < 8; ++mt) acc[mt] = (f32x4){0.f, 0.f, 0.f, 0.f};

        const float* xr = &xlds[wid][bcur][(size_t)row_l * 128];
        #pragma unroll
        for (int kk = 0; kk < 4; ++kk) {
            const int q0 = kk * 8 + lg * 2;
            f32x4 a0 = *reinterpret_cast<const f32x4*>(xr + ((q0)     ^ row_l) * 4);
            f32x4 a1 = *reinterpret_cast<const f32x4*>(xr + ((q0 + 1) ^ row_l) * 4);
            bf16x8 xb;
            #pragma unroll
            for (int i = 0; i < 4; ++i) {
                xb[i]     = (__bf16)a0[i];
                xb[i + 4] = (__bf16)a1[i];
            }
            #pragma unroll
            for (int mt = 0; mt < 8; ++mt)
                acc[mt] = __builtin_amdgcn_mfma_f32_16x16x32_bf16(
                    wfrag[mt * 4 + kk], xb, acc[mt], 0, 0, 0);
        }

        // store: node = st*8 + l15 (l15<8), channels mt*16 + lg*4 .. +4
        if (l15 < 8) {
            const int node = st * 8 + l15;
            __bf16* op = oph + (size_t)node * HF + lg * 4;
            #pragma unroll
            for (int mt = 0; mt < 8; ++mt) {
                bf16x4 o4;
                #pragma unroll
                for (int r = 0; r < 4; ++r) o4[r] = (__bf16)acc[mt][r];
                *reinterpret_cast<bf16x4*>(op + mt * 16) = o4;
            }
        }

        bcur = (bcur + 1) % 3;
        st = st1;
        ++it;
    }
}

// ================= Kernel 2: per-edge score (pure gather, 4 edges/sub) =====
// score[e] = W2 . relu(u[src[e]] + v[dst[e]] + b1) + b2
__global__ __launch_bounds__(256) void edge_score_kernel(
    const __bf16* __restrict__ u, const __bf16* __restrict__ v,
    const int* __restrict__ sidx, const int* __restrict__ didx,
    const float* __restrict__ W2, const float* __restrict__ b1,
    const float* __restrict__ b2,
    float* __restrict__ out, int nEdges)
{
    const int tid = threadIdx.x;
    const int sub = tid >> 4;        // 0..15
    const int l16 = tid & 15;

    const int ebase = blockIdx.x * 64 + sub;   // edges ebase + {0,16,32,48}

    float w2v[8], b1v[8];
    #pragma unroll
    for (int j = 0; j < 8; ++j) {
        w2v[j] = W2[l16 * 8 + j];
        b1v[j] = b1[l16 * 8 + j];
    }
    const float b2v = b2[0];

    int e[4], si[4], di[4];
    #pragma unroll
    for (int q = 0; q < 4; ++q) {
        e[q] = ebase + q * 16;
        const int c = min(e[q], nEdges - 1);
        si[q] = sidx[c];
        di[q] = didx[c];
    }

    bf16x8 uv[4], vv[4];
    #pragma unroll
    for (int q = 0; q < 4; ++q) {
        uv[q] = *reinterpret_cast<const bf16x8*>(u + (size_t)si[q] * HF + l16 * 8);
        vv[q] = *reinterpret_cast<const bf16x8*>(v + (size_t)di[q] * HF + l16 * 8);
    }

    float s[4] = {0.f, 0.f, 0.f, 0.f};
    #pragma unroll
    for (int q = 0; q < 4; ++q)
        #pragma unroll
        for (int j = 0; j < 8; ++j)
            s[q] += fmaxf((float)uv[q][j] + (float)vv[q][j] + b1v[j], 0.f) * w2v[j];

    #pragma unroll
    for (int off = 1; off < 16; off <<= 1)
        #pragma unroll
        for (int q = 0; q < 4; ++q)
            s[q] += __shfl_xor(s[q], off, 64);

    if (l16 == 0) {
        #pragma unroll
        for (int q = 0; q < 4; ++q)
            if (e[q] < nEdges) out[e[q]] = s[q] + b2v;
    }
}

// ================= Fallback: fused single kernel (round-1) =================
__global__ __launch_bounds__(256, 2) void edge_mlp_kernel(
    const float* __restrict__ x_src, const float* __restrict__ x_dst,
    const int*   __restrict__ src_idx, const int* __restrict__ dst_idx,
    const float* __restrict__ W1, const float* __restrict__ b1,
    const float* __restrict__ W2, const float* __restrict__ b2,
    float* __restrict__ out, int nEdges)
{
    __shared__ __align__(16) __bf16 w1lds[64 * 64 * 8];

    const int tid  = threadIdx.x;
    const int lane = tid & 63;
    const int wid  = tid >> 6;
    const int l15  = lane & 15;
    const int lg   = lane >> 4;

    for (int p = wid; p < 64; p += 4) {
        const int n   = p >> 3;
        const int kk  = p & 7;
        const float* src = W1 + (n * 16 + l15) * W1K + kk * 32 + lg * 8;
        bf16x8 w8;
        #pragma unroll
        for (int i = 0; i < 8; ++i) w8[i] = (__bf16)src[i];
        *reinterpret_cast<bf16x8*>(&w1lds[(p * 64 + lane) * 8]) = w8;
    }
    __syncthreads();

    float w2v[8], b1v[8];
    #pragma unroll
    for (int n = 0; n < 8; ++n) {
        w2v[n] = W2[n * 16 + l15];
        b1v[n] = b1[n * 16 + l15];
    }
    const float b2v = b2[0];

    const int ntiles = nEdges / 256;
    for (int t = blockIdx.x; t < ntiles; t += gridDim.x) {
        const int ebase = t * 256 + wid * 64;

        const float* srow[4];
        const float* drow[4];
        #pragma unroll
        for (int m = 0; m < 4; ++m) {
            const int e  = ebase + m * 16 + l15;
            srow[m] = x_src + (size_t)src_idx[e] * HF + lg * 8;
            drow[m] = x_dst + (size_t)dst_idx[e] * HF + lg * 8;
        }

        f32x4 acc[4][8];
        #pragma unroll
        for (int m = 0; m < 4; ++m)
            #pragma unroll
            for (int n = 0; n < 8; ++n)
                acc[m][n] = (f32x4){0.f, 0.f, 0.f, 0.f};

        #pragma unroll
        for (int kk = 0; kk < 8; ++kk) {
            bf16x8 a[4];
            #pragma unroll
            for (int m = 0; m < 4; ++m) {
                const float* p = (kk < 4) ? (srow[m] + kk * 32)
                                          : (drow[m] + (kk - 4) * 32);
                f32x4 u0 = *reinterpret_cast<const f32x4*>(p);
                f32x4 u1 = *reinterpret_cast<const f32x4*>(p + 4);
                bf16x8 av;
                #pragma unroll
                for (int i = 0; i < 4; ++i) {
                    av[i]     = (__bf16)u0[i];
                    av[i + 4] = (__bf16)u1[i];
                }
                a[m] = av;
            }
            #pragma unroll
            for (int n = 0; n < 8; ++n) {
                bf16x8 bfrag = *reinterpret_cast<const bf16x8*>(
                    &w1lds[((n * 8 + kk) * 64 + lane) * 8]);
                #pragma unroll
                for (int m = 0; m < 4; ++m) {
                    acc[m][n] = __builtin_amdgcn_mfma_f32_16x16x32_bf16(
                        a[m], bfrag, acc[m][n], 0, 0, 0);
                }
            }
        }

        #pragma unroll
        for (int m = 0; m < 4; ++m) {
            float part[4];
            #pragma unroll
            for (int r = 0; r < 4; ++r) {
                float s = 0.f;
                #pragma unroll
                for (int n = 0; n < 8; ++n) {
                    float hv = acc[m][n][r] + b1v[n];
                    s += fmaxf(hv, 0.f) * w2v[n];
                }
                part[r] = s;
            }
            #pragma unroll
            for (int off = 1; off < 16; off <<= 1) {
                #pragma unroll
                for (int r = 0; r < 4; ++r)
                    part[r] += __shfl_xor(part[r], off, 64);
            }
            if (l15 == m) {
                f32x4 v4 = { part[0] + b2v, part[1] + b2v,
                             part[2] + b2v, part[3] + b2v };
                *reinterpret_cast<f32x4*>(&out[ebase + m * 16 + lg * 4]) = v4;
            }
        }
    }
}

extern "C" void kernel_launch(void* const* d_in, const int* in_sizes, int n_in,
                              void* d_out, int out_size, void* d_ws, size_t ws_size,
                              hipStream_t stream) {
    const float* x_src  = (const float*)d_in[0];
    const float* x_dst  = (const float*)d_in[1];
    const int*   sidx   = (const int*)d_in[2];
    const int*   didx   = (const int*)d_in[3];
    const float* W1     = (const float*)d_in[4];
    const float* b1     = (const float*)d_in[5];
    const float* W2     = (const float*)d_in[6];
    const float* b2     = (const float*)d_in[7];
    float* out = (float*)d_out;

    const int nEdges = in_sizes[2];
    const int nNodes = in_sizes[0] / HF;

    const size_t uvsz   = (size_t)2 * nNodes * HF;                  // elems
    const size_t needed = uvsz * sizeof(__bf16) + 64 * 1024;        // u+v+wf
    if (ws_size >= needed && (nNodes & 7) == 0) {
        __bf16* u  = (__bf16*)d_ws;
        __bf16* v  = u + (size_t)nNodes * HF;
        __bf16* wf = u + uvsz;

        w1_repack<<<2, 256, 0, stream>>>(W1, wf);

        node_precompute14<<<256, 512, 0, stream>>>(
            x_src, x_dst, wf, u, v, nNodes);

        const int egrid = (nEdges + 63) / 64;
        edge_score_kernel<<<egrid, 256, 0, stream>>>(
            u, v, sidx, didx, W2, b1, b2, out, nEdges);
    } else {
        edge_mlp_kernel<<<512, 256, 0, stream>>>(
            x_src, x_dst, sidx, didx, W1, b1, W2, b2, out, nEdges);
    }
}